// Round 9
// baseline (91.731 us; speedup 1.0000x reference)
//
#include <hip/hip_runtime.h>

// Problem constants (from reference)
#define BSZ 128
#define NPTS 16384
#define GL 48
#define GW 20
#define GH 18
#define VOX_PER_B (GL * GW * GH)       // 17280 floats = 67.5 KB
#define NTOT (BSZ * NPTS)              // 2,097,152 points
#define BLOCK 1024
#define NWAVES (BLOCK / 64)            // 16
#define BLOCKS_PER_BATCH 2             // voxel HBM traffic = 2 x 8.85 MB by construction
#define NBLK (BSZ * BLOCKS_PER_BATCH)             // 256 blocks -> 1 block/CU, 16 waves
#define PTS_PER_BLOCK (NPTS / BLOCKS_PER_BATCH)   // 8192
#define GROUP_PTS 4                                // consecutive points per thread-group
#define VEC4S (VOX_PER_B / 4)                      // 4320 float4s to stage
#define STAGE_FULL 4                               // 4*1024 = 4096 full iterations
#define STAGE_TAIL (VEC4S - STAGE_FULL * BLOCK)    // 224-thread tail

// native clang vector type — __builtin_nontemporal_load rejects HIP_vector_type
typedef float nfloat4 __attribute__((ext_vector_type(4)));

__device__ __forceinline__ float clampf(float v, float lo, float hi) {
    return fminf(fmaxf(v, lo), hi);    // -> v_med3_f32
}

// One point's trilinear sample + huber, minimal-VALU form (see R6 notes):
// no divides, boundary cases folded into med3-clamped weights (exactly
// reproduces reference both-corners-clamped semantics; measured absmax 0.0),
// 8 corners = 4 ds_read2_b32 at constant offsets from 2 addresses.
__device__ __forceinline__ float point_loss(const float* __restrict__ vlds,
                                            float px, float py, float pz, float hg)
{
    const float xs = fmaf(px, 10.0f, 24.0f);           // (px+2.4)/0.1
    const float ys = fmaf(py, 10.0f, 10.0f);           // (py+1.0)/0.1
    const float zs = fmaf(pz, 10.0f, hg * 5.0f);       // (pz+hg/2)/0.1

    const float xbf = clampf(floorf(xs), 0.0f, (float)(GL - 2));
    const float ybf = clampf(floorf(ys), 0.0f, (float)(GW - 2));
    const float zbf = clampf(floorf(zs), 0.0f, (float)(GH - 2));

    const float tx = clampf(xs - xbf, 0.0f, 1.0f);
    const float ty = clampf(ys - ybf, 0.0f, 1.0f);
    const float tz = clampf(zs - zbf, 0.0f, 1.0f);
    const float sx = 1.0f - tx, sy = 1.0f - ty, sz = 1.0f - tz;

    const int xb = (int)xbf;
    const int yb = (int)ybf;
    const int zb = (int)zbf;

    const float* q  = vlds + (xb * (GW * GH) + yb * GH + zb);
    const float* q2 = q + (GW * GH);                   // x+1 plane

    const float c000 = q[0],   c001 = q[1];            // ds_read2 (0,1)
    const float c010 = q[GH],  c011 = q[GH + 1];       // ds_read2 (18,19)
    const float c100 = q2[0],  c101 = q2[1];
    const float c110 = q2[GH], c111 = q2[GH + 1];

    const float p00 = fmaf(tz, c001, sz * c000);
    const float p01 = fmaf(tz, c011, sz * c010);
    const float p10 = fmaf(tz, c101, sz * c100);
    const float p11 = fmaf(tz, c111, sz * c110);
    const float py0 = fmaf(ty, p01, sy * p00);
    const float py1 = fmaf(ty, p11, sy * p10);
    const float sdf = fmaf(tx, py1, sx * py0);

    const float ax = fabsf(sdf);
    return (ax < 1.0f) ? 0.5f * sdf * sdf : ax - 0.5f;
}

__global__ __launch_bounds__(BLOCK, 4) void trilinear_huber_lds_kernel(
    const float* __restrict__ voxels,   // [B, GL, GW, GH]
    const float* __restrict__ pts,      // [B, N, 3]
    const float* __restrict__ hgt,      // [B, N]
    float* __restrict__ out)            // [1]
{
    __shared__ float vlds[VOX_PER_B];   // 67.5 KB
    __shared__ float wsum[NWAVES];

    // Pair the two blocks of one batch mod 8 (same-XCD L2 reuse of the voxel
    // slice; traffic no longer depends on it, it's a bonus).
    const int bid  = blockIdx.x;
    const int xcd  = bid & 7;
    const int slot = (bid >> 3) & 15;
    const int half = bid >> 7;          // [0, 2)
    const int b    = xcd * 16 + slot;   // batch id [0, 128)
    const int tid  = threadIdx.x;
    const int lane = tid & 63;
    const int wid  = tid >> 6;

    const int pbase = b * NPTS + half * PTS_PER_BLOCK;
    const int p0 = pbase + tid * GROUP_PTS;          // group 0 (4 consecutive pts)
    const int p1 = p0 + BLOCK * GROUP_PTS;           // group 1

    // Prefetch group-0 points so this HBM stream overlaps voxel staging.
    // NON-TEMPORAL: pts/hgt are streamed once (33.6 MB total) — keep them from
    // evicting the voxel slices (L2-resident for the sibling block's staging).
    const nfloat4* pp0 = (const nfloat4*)(pts + 3 * (size_t)p0);   // 48 B aligned
    const nfloat4 g0a = __builtin_nontemporal_load(pp0 + 0);
    const nfloat4 g0b = __builtin_nontemporal_load(pp0 + 1);
    const nfloat4 g0c = __builtin_nontemporal_load(pp0 + 2);
    const nfloat4 h0  = __builtin_nontemporal_load((const nfloat4*)(hgt + p0));

    // Stage batch voxel slice into LDS (fully-unrolled float4 copy; normal
    // loads -> voxel lines stay cached in L2 for the sibling block).
    {
        const float4* vb4 = (const float4*)(voxels + (size_t)b * VOX_PER_B);
        float4* lds4 = (float4*)vlds;
        #pragma unroll
        for (int k = 0; k < STAGE_FULL; ++k)
            lds4[tid + k * BLOCK] = vb4[tid + k * BLOCK];
        if (tid < STAGE_TAIL)
            lds4[tid + STAGE_FULL * BLOCK] = vb4[tid + STAGE_FULL * BLOCK];
    }
    __syncthreads();

    // Issue group-1 prefetch (non-temporal) before computing group 0.
    const nfloat4* pp1 = (const nfloat4*)(pts + 3 * (size_t)p1);
    const nfloat4 g1a = __builtin_nontemporal_load(pp1 + 0);
    const nfloat4 g1b = __builtin_nontemporal_load(pp1 + 1);
    const nfloat4 g1c = __builtin_nontemporal_load(pp1 + 2);
    const nfloat4 h1  = __builtin_nontemporal_load((const nfloat4*)(hgt + p1));

    float acc = 0.0f;
    acc += point_loss(vlds, g0a.x, g0a.y, g0a.z, h0.x);
    acc += point_loss(vlds, g0a.w, g0b.x, g0b.y, h0.y);
    acc += point_loss(vlds, g0b.z, g0b.w, g0c.x, h0.z);
    acc += point_loss(vlds, g0c.y, g0c.z, g0c.w, h0.w);
    acc += point_loss(vlds, g1a.x, g1a.y, g1a.z, h1.x);
    acc += point_loss(vlds, g1a.w, g1b.x, g1b.y, h1.y);
    acc += point_loss(vlds, g1b.z, g1b.w, g1c.x, h1.z);
    acc += point_loss(vlds, g1c.y, g1c.z, g1c.w, h1.w);

    // wave-64 shuffle reduction, then block reduction, one atomic
    #pragma unroll
    for (int off = 32; off > 0; off >>= 1)
        acc += __shfl_down(acc, off, 64);

    if (lane == 0) wsum[wid] = acc;
    __syncthreads();

    if (tid == 0) {
        float bsum = 0.0f;
        #pragma unroll
        for (int w = 0; w < NWAVES; ++w) bsum += wsum[w];
        atomicAdd(out, bsum * (1.0f / (float)NTOT));
    }
}

extern "C" void kernel_launch(void* const* d_in, const int* in_sizes, int n_in,
                              void* d_out, int out_size, void* d_ws, size_t ws_size,
                              hipStream_t stream) {
    const float* voxels = (const float*)d_in[0];   // [B, 48, 20, 18]
    const float* pts    = (const float*)d_in[1];   // [B, N, 3]
    const float* hgt    = (const float*)d_in[2];   // [B, N]
    float* out = (float*)d_out;

    // d_out is poisoned to 0xAA before every timed replay — zero it in-graph.
    (void)hipMemsetAsync(out, 0, sizeof(float), stream);

    trilinear_huber_lds_kernel<<<NBLK, BLOCK, 0, stream>>>(voxels, pts, hgt, out);
}

// Round 10
// 87.527 us; speedup vs baseline: 1.0480x; 1.0480x over previous
//
#include <hip/hip_runtime.h>

// Problem constants (from reference)
#define BSZ 128
#define NPTS 16384
#define GL 48
#define GW 20
#define GH 18
#define VOX_PER_B (GL * GW * GH)       // 17280 floats = 67.5 KB
#define NTOT (BSZ * NPTS)              // 2,097,152 points
#define BLOCK 1024
#define NWAVES (BLOCK / 64)            // 16
#define BLOCKS_PER_BATCH 2             // voxel HBM traffic = 2 x 8.85 MB by construction
#define NBLK (BSZ * BLOCKS_PER_BATCH)             // 256 blocks -> 1 block/CU, 16 waves
#define PTS_PER_BLOCK (NPTS / BLOCKS_PER_BATCH)   // 8192
#define GROUP_PTS 4                                // consecutive points per thread-group
#define VEC4S (VOX_PER_B / 4)                      // 4320 float4s to stage
#define STAGE_FULL 4                               // 4*1024 = 4096 full iterations
#define STAGE_TAIL (VEC4S - STAGE_FULL * BLOCK)    // 224-thread tail

__device__ __forceinline__ float clampf(float v, float lo, float hi) {
    return fminf(fmaxf(v, lo), hi);    // -> v_med3_f32
}

// One point's trilinear sample + huber, minimal-VALU form (see R6 notes):
// no divides, boundary cases folded into med3-clamped weights (exactly
// reproduces reference both-corners-clamped semantics; measured absmax 0.0),
// 8 corners = 4 ds_read2_b32 at constant offsets from 2 addresses.
__device__ __forceinline__ float point_loss(const float* __restrict__ vlds,
                                            float px, float py, float pz, float hg)
{
    const float xs = fmaf(px, 10.0f, 24.0f);           // (px+2.4)/0.1
    const float ys = fmaf(py, 10.0f, 10.0f);           // (py+1.0)/0.1
    const float zs = fmaf(pz, 10.0f, hg * 5.0f);       // (pz+hg/2)/0.1

    const float xbf = clampf(floorf(xs), 0.0f, (float)(GL - 2));
    const float ybf = clampf(floorf(ys), 0.0f, (float)(GW - 2));
    const float zbf = clampf(floorf(zs), 0.0f, (float)(GH - 2));

    const float tx = clampf(xs - xbf, 0.0f, 1.0f);
    const float ty = clampf(ys - ybf, 0.0f, 1.0f);
    const float tz = clampf(zs - zbf, 0.0f, 1.0f);
    const float sx = 1.0f - tx, sy = 1.0f - ty, sz = 1.0f - tz;

    const int xb = (int)xbf;
    const int yb = (int)ybf;
    const int zb = (int)zbf;

    const float* q  = vlds + (xb * (GW * GH) + yb * GH + zb);
    const float* q2 = q + (GW * GH);                   // x+1 plane

    const float c000 = q[0],   c001 = q[1];            // ds_read2 (0,1)
    const float c010 = q[GH],  c011 = q[GH + 1];       // ds_read2 (18,19)
    const float c100 = q2[0],  c101 = q2[1];
    const float c110 = q2[GH], c111 = q2[GH + 1];

    const float p00 = fmaf(tz, c001, sz * c000);
    const float p01 = fmaf(tz, c011, sz * c010);
    const float p10 = fmaf(tz, c101, sz * c100);
    const float p11 = fmaf(tz, c111, sz * c110);
    const float py0 = fmaf(ty, p01, sy * p00);
    const float py1 = fmaf(ty, p11, sy * p10);
    const float sdf = fmaf(tx, py1, sx * py0);

    const float ax = fabsf(sdf);
    return (ax < 1.0f) ? 0.5f * sdf * sdf : ax - 0.5f;
}

__global__ __launch_bounds__(BLOCK, 4) void trilinear_huber_lds_kernel(
    const float* __restrict__ voxels,   // [B, GL, GW, GH]
    const float* __restrict__ pts,      // [B, N, 3]
    const float* __restrict__ hgt,      // [B, N]
    float* __restrict__ out)            // [1]
{
    __shared__ float vlds[VOX_PER_B];   // 67.5 KB
    __shared__ float wsum[NWAVES];

    // Pair the two blocks of one batch mod 8 (possible same-XCD L2 bonus;
    // correctness/traffic do not depend on it).
    const int bid  = blockIdx.x;
    const int xcd  = bid & 7;
    const int slot = (bid >> 3) & 15;
    const int half = bid >> 7;          // [0, 2)
    const int b    = xcd * 16 + slot;   // batch id [0, 128)
    const int tid  = threadIdx.x;
    const int lane = tid & 63;
    const int wid  = tid >> 6;

    const int pbase = b * NPTS + half * PTS_PER_BLOCK;
    const int p0 = pbase + tid * GROUP_PTS;          // group 0 (4 consecutive pts)
    const int p1 = p0 + BLOCK * GROUP_PTS;           // group 1

    // Prefetch group-0 points so this HBM stream overlaps voxel staging.
    // Plain (cached) loads: R9 measured non-temporal loads as a 4 us
    // regression — L1/L2 line reuse within the 48 B/thread pattern matters.
    const float4* pp0 = (const float4*)(pts + 3 * (size_t)p0);   // 48 B aligned
    const float4 g0a = pp0[0], g0b = pp0[1], g0c = pp0[2];
    const float4 h0  = *(const float4*)(hgt + p0);

    // Stage batch voxel slice into LDS (fully-unrolled float4 copy).
    {
        const float4* vb4 = (const float4*)(voxels + (size_t)b * VOX_PER_B);
        float4* lds4 = (float4*)vlds;
        #pragma unroll
        for (int k = 0; k < STAGE_FULL; ++k)
            lds4[tid + k * BLOCK] = vb4[tid + k * BLOCK];
        if (tid < STAGE_TAIL)
            lds4[tid + STAGE_FULL * BLOCK] = vb4[tid + STAGE_FULL * BLOCK];
    }
    __syncthreads();

    // Issue group-1 prefetch before computing group 0.
    const float4* pp1 = (const float4*)(pts + 3 * (size_t)p1);
    const float4 g1a = pp1[0], g1b = pp1[1], g1c = pp1[2];
    const float4 h1  = *(const float4*)(hgt + p1);

    float acc = 0.0f;
    acc += point_loss(vlds, g0a.x, g0a.y, g0a.z, h0.x);
    acc += point_loss(vlds, g0a.w, g0b.x, g0b.y, h0.y);
    acc += point_loss(vlds, g0b.z, g0b.w, g0c.x, h0.z);
    acc += point_loss(vlds, g0c.y, g0c.z, g0c.w, h0.w);
    acc += point_loss(vlds, g1a.x, g1a.y, g1a.z, h1.x);
    acc += point_loss(vlds, g1a.w, g1b.x, g1b.y, h1.y);
    acc += point_loss(vlds, g1b.z, g1b.w, g1c.x, h1.z);
    acc += point_loss(vlds, g1c.y, g1c.z, g1c.w, h1.w);

    // wave-64 shuffle reduction, then block reduction, one atomic
    #pragma unroll
    for (int off = 32; off > 0; off >>= 1)
        acc += __shfl_down(acc, off, 64);

    if (lane == 0) wsum[wid] = acc;
    __syncthreads();

    if (tid == 0) {
        float bsum = 0.0f;
        #pragma unroll
        for (int w = 0; w < NWAVES; ++w) bsum += wsum[w];
        atomicAdd(out, bsum * (1.0f / (float)NTOT));
    }
}

extern "C" void kernel_launch(void* const* d_in, const int* in_sizes, int n_in,
                              void* d_out, int out_size, void* d_ws, size_t ws_size,
                              hipStream_t stream) {
    const float* voxels = (const float*)d_in[0];   // [B, 48, 20, 18]
    const float* pts    = (const float*)d_in[1];   // [B, N, 3]
    const float* hgt    = (const float*)d_in[2];   // [B, N]
    float* out = (float*)d_out;

    // d_out is poisoned to 0xAA before every timed replay — zero it in-graph.
    (void)hipMemsetAsync(out, 0, sizeof(float), stream);

    trilinear_huber_lds_kernel<<<NBLK, BLOCK, 0, stream>>>(voxels, pts, hgt, out);
}